// Round 13
// baseline (33.225 us; speedup 1.0000x reference)
//
#include <hip/hip_runtime.h>
#include <hip/hip_bf16.h>

#define NUM_CLASSES 10000
#define NUM_PROXIES 10
#define EMB_DIM 128
#define HALF_B 128
#define MARGIN_DELTA 0.01f
#define LAMBDA_ 20.0f
#define INV_GAMMA 10.0f   // 1/GAMMA

#define CB 8                        // classes per tile
#define ROWS (CB * NUM_PROXIES)     // 80 proxy rows per tile
#define MF 5                        // 80/16 m-fragments
#define KSTEPS 4                    // 128/32
#define NTILE 1250                  // 1250 blocks x 1 tile

// C: col-major, 256 cols x 40 words (160 B) with word-XOR swizzle (R7-proven
// correct on HW): logical word lw of col c stored at word (lw ^ ((c>>2)&7)).
// bf16 stage (20480 B) aliases inside C. 40960 B = 160KiB/4 -> 4 blocks/CU
// when regs <= 128 (JIT bfrag keeps MFMA-phase peak ~110).
#define CSTRIDE 160
#define SMEMSZ (CSTRIDE * 256)             // 40960 B

typedef __bf16 bf16x8 __attribute__((ext_vector_type(8)));
typedef __bf16 bf16x4 __attribute__((ext_vector_type(4)));
typedef float f32x4 __attribute__((ext_vector_type(4)));
typedef unsigned short ushort_t;

__device__ __forceinline__ unsigned int pk2bf(float a, float b) {
    __bf16 ha = (__bf16)a, hb = (__bf16)b;
    return (unsigned int)__builtin_bit_cast(ushort_t, ha) |
           ((unsigned int)__builtin_bit_cast(ushort_t, hb) << 16);
}

// ---------------------------------------------------------------------------
// Kernel 0: pack feat into MFMA B-fragment layout ONCE (64 KB, L2-resident).
// ---------------------------------------------------------------------------
__global__ __launch_bounds__(256) void pack_feat_kernel(
    const float* __restrict__ feat,    // [256][128] f32
    bf16x8* __restrict__ featPack)     // [4096] entries of 16 B
{
    const int gid = blockIdx.x * 256 + threadIdx.x;   // 0..2047
    #pragma unroll
    for (int half = 0; half < 2; ++half) {
        int e    = gid + half * 2048;                 // 0..4095
        int lane = e & 63;
        int t    = (e >> 6) & 3;
        int nf   = (e >> 8) & 3;
        int w    = (e >> 10) & 3;
        int l15  = lane & 15;
        int g    = lane >> 4;
        int col  = w * 64 + nf * 16 + l15;
        const float4* fp = (const float4*)(feat + (size_t)col * EMB_DIM + t * 32 + g * 8);
        float4 v0 = fp[0], v1 = fp[1];
        featPack[e] = (bf16x8){ (__bf16)v0.x, (__bf16)v0.y, (__bf16)v0.z, (__bf16)v0.w,
                                (__bf16)v1.x, (__bf16)v1.y, (__bf16)v1.z, (__bf16)v1.w };
    }
}

// ---------------------------------------------------------------------------
// Kernel 1: champion phase structure (stage -> MFMA -> transpose -> softmax),
// 1250 blocks x 256 threads, with exactly three individually-validated deltas
// to reach 4 blocks/CU: (a) stride-160 word-XOR C (R7), (b) JIT bfrag (R6),
// (c) Ps2 direct-store tail, no rowsum/final barrier (R8). Everything else
// byte-identical to the 30.0us champion. THE unconfounded occupancy test.
// ---------------------------------------------------------------------------
__global__ __launch_bounds__(256, 4) void compute_S_kernel(
    const float* __restrict__ prox,     // [10000][10][128] f32
    const bf16x8* __restrict__ featPack,// [4096]
    const int* __restrict__ labels,     // [256]
    float* __restrict__ Ps2,            // [1250][256] 4-class partials
    float* __restrict__ sc)             // [128]
{
    __shared__ __align__(16) char smem[SMEMSZ];

    const int tid     = threadIdx.x;
    const int lane    = tid & 63;
    const int w       = tid >> 6;
    const int l15     = lane & 15;
    const int g       = lane >> 4;
    const int tileIdx = blockIdx.x;
    const int lab     = labels[tid & 127];

    // ---- issue stage loads first (80x128 f32 tile, linear & coalesced) ----
    const char* pbase = (const char*)prox + (size_t)tileIdx * (ROWS * EMB_DIM * 4);
    float4 sv[10];
    #pragma unroll
    for (int j = 0; j < 10; ++j)
        sv[j] = *(const float4*)(pbase + ((size_t)(j * 256 + tid) << 4));

    // ---- convert stage to bf16, XOR-swizzled ds_write (champion mapping) ----
    #pragma unroll
    for (int j = 0; j < 10; ++j) {
        int cid = j * 256 + tid;
        int row = cid >> 5;
        int c32 = cid & 31;
        int off = row * 256 + ((((c32 >> 1) ^ (row & 7))) << 4) + ((c32 & 1) << 3);
        bf16x4 o = { (__bf16)sv[j].x, (__bf16)sv[j].y, (__bf16)sv[j].z, (__bf16)sv[j].w };
        *(bf16x4*)(smem + off) = o;
    }

    __syncthreads();                       // stage visible

    // ---- MFMA: 20 ds_read_b128 + 80 MFMA per wave; bfrag JIT per K-step ----
    f32x4 acc[MF][4];
    #pragma unroll
    for (int mf = 0; mf < MF; ++mf)
        #pragma unroll
        for (int nf = 0; nf < 4; ++nf)
            acc[mf][nf] = (f32x4){0.f, 0.f, 0.f, 0.f};

    __builtin_amdgcn_s_setprio(1);
    #pragma unroll
    for (int t = 0; t < KSTEPS; ++t) {
        bf16x8 bt[4];
        #pragma unroll
        for (int nf = 0; nf < 4; ++nf)
            bt[nf] = featPack[((w * 4 + nf) * 4 + t) * 64 + lane];
        #pragma unroll
        for (int mf = 0; mf < MF; ++mf) {
            int row = mf * 16 + l15;
            int ck  = (t * 4 + g) ^ (row & 7);
            bf16x8 a = *(const bf16x8*)(smem + row * 256 + (ck << 4));
            #pragma unroll
            for (int nf = 0; nf < 4; ++nf)
                acc[mf][nf] = __builtin_amdgcn_mfma_f32_16x16x32_bf16(
                    a, bt[nf], acc[mf][nf], 0, 0, 0);
        }
    }
    __builtin_amdgcn_s_setprio(0);

    __syncthreads();                       // WAR: stage reads done before C writes

    // ---- transpose dots into C (col-major 160B, word-XOR swizzle, R7) ----
    char* C = smem;
    #pragma unroll
    for (int mf = 0; mf < MF; ++mf) {
        #pragma unroll
        for (int nf = 0; nf < 4; ++nf) {
            int col = w * 64 + nf * 16 + l15;
            int u   = (col >> 2) & 7;
            int w0  = mf * 8 + g * 2;      // even logical word (rows 2w0, 2w0+1)
            unsigned int lo = pk2bf(acc[mf][nf][0], acc[mf][nf][1]);
            unsigned int hi = pk2bf(acc[mf][nf][2], acc[mf][nf][3]);
            char* colb = C + col * CSTRIDE;
            *(unsigned int*)(colb + ((w0 ^ u) << 2))       = lo;
            *(unsigned int*)(colb + (((w0 + 1) ^ u) << 2)) = hi;
        }
    }
    __syncthreads();                       // C visible to softmax

    // ---- k=10 softmax per (col, class); pair-avg cols i / i+128 ----
    const int colh  = tid & 127;
    const int chalf = tid >> 7;
    float lsum = 0.f;
    #pragma unroll
    for (int cl4 = 0; cl4 < 4; ++cl4) {
        int cl = chalf * 4 + cl4;
        float Ssum = 0.f;
        #pragma unroll
        for (int h = 0; h < 2; ++h) {
            int col = colh + h * 128;
            int u   = (col >> 2) & 7;
            const char* base = C + col * CSTRIDE;
            float d[10];
            #pragma unroll
            for (int p5 = 0; p5 < 5; ++p5) {
                unsigned int pr = *(const unsigned int*)(base + (((cl * 5 + p5) ^ u) << 2));
                // exact-bit unpack of the two bf16 halves
                d[2 * p5]     = __builtin_bit_cast(float, pr << 16);
                d[2 * p5 + 1] = __builtin_bit_cast(float, pr & 0xFFFF0000u);
            }
            float sw = 0.f, sd = 0.f;
            #pragma unroll
            for (int k = 0; k < NUM_PROXIES; ++k) {
                float e = __expf(d[k] * INV_GAMMA);   // no max-shift: bounded
                sw += e;
                sd += e * d[k];
            }
            Ssum += sd / sw;
        }
        float Savg = 0.5f * Ssum;
        int c = tileIdx * CB + cl;
        float x = LAMBDA_ * Savg;
        if (c == lab) {
            x -= LAMBDA_ * MARGIN_DELTA;
            sc[colh] = x;
        }
        lsum += __expf(x);
    }

    // 4-class partial straight to global: no rowsum, no final barrier (R8).
    Ps2[(size_t)tileIdx * 256 + tid] = lsum;
}

// ---------------------------------------------------------------------------
// Kernel 2: partial sum of Ps2 over tiles, folding (i, i+128) per tile with
// the champion's (lo+hi) pairing. 50 blocks x 25 tiles (parallel shape is
// load-bearing: 1-block variants cost ~+9us).
// ---------------------------------------------------------------------------
__global__ __launch_bounds__(256) void psum_kernel(
    const float* __restrict__ Ps2,     // [1250][256]
    float* __restrict__ Psum2)         // [50][128]
{
    const int b0  = blockIdx.x * 25;
    const int tid = threadIdx.x;
    const int r   = tid >> 5;    // 0..7
    const int c   = tid & 31;    // float4 column group

    float4 s = make_float4(0.f, 0.f, 0.f, 0.f);
    #pragma unroll
    for (int j = 0; j < 4; ++j) {
        int b = r + 8 * j;
        if (b < 25) {
            const float* row = Ps2 + (size_t)(b0 + b) * 256;
            float4 lo = *(const float4*)(row + c * 4);
            float4 hi = *(const float4*)(row + 128 + c * 4);
            s.x += (lo.x + hi.x);
            s.y += (lo.y + hi.y);
            s.z += (lo.z + hi.z);
            s.w += (lo.w + hi.w);
        }
    }

    __shared__ float red[8][HALF_B];
    *(float4*)&red[r][c * 4] = s;
    __syncthreads();
    if (tid < HALF_B) {
        float t = 0.f;
        #pragma unroll
        for (int rr = 0; rr < 8; ++rr) t += red[rr][tid];
        Psum2[blockIdx.x * HALF_B + tid] = t;
    }
}

// ---------------------------------------------------------------------------
// Kernel 3: denom[i] = log(sum_b Psum2[b][i]); loss = -mean(sc[i]-denom[i])
// ---------------------------------------------------------------------------
__global__ __launch_bounds__(128) void finalize_kernel(
    const float* __restrict__ Psum2,   // [50][128]
    const float* __restrict__ sc,      // [128]
    float* __restrict__ out)
{
    const int i = threadIdx.x;   // 0..127
    float t = 0.f;
    #pragma unroll
    for (int b = 0; b < 50; ++b) t += Psum2[b * HALF_B + i];
    float part = sc[i] - __logf(t);

    __shared__ float buf[HALF_B];
    buf[i] = part;
    __syncthreads();
    #pragma unroll
    for (int off = 64; off >= 1; off >>= 1) {
        if (i < off) buf[i] += buf[i + off];
        __syncthreads();
    }
    if (i == 0) out[0] = -buf[0] / (float)HALF_B;
}

extern "C" void kernel_launch(void* const* d_in, const int* in_sizes, int n_in,
                              void* d_out, int out_size, void* d_ws, size_t ws_size,
                              hipStream_t stream) {
    const float* feat   = (const float*)d_in[0];   // [256][128] f32
    const int*   labels = (const int*)d_in[1];     // [256]
    const float* prox   = (const float*)d_in[2];   // [10000][10][128] f32
    float* out = (float*)d_out;

    float* Ps2   = (float*)d_ws;                                   // 1,280,000 B
    float* sc    = (float*)((char*)d_ws + 1280000);                // 512 B
    float* Psum2 = (float*)((char*)d_ws + 1280512);                // 25600 B
    bf16x8* featPack = (bf16x8*)((char*)d_ws + 1306112);           // 65536 B

    pack_feat_kernel<<<8, 256, 0, stream>>>(feat, featPack);
    compute_S_kernel<<<NTILE, 256, 0, stream>>>(prox, featPack, labels, Ps2, sc);
    psum_kernel<<<50, 256, 0, stream>>>(Ps2, Psum2);
    finalize_kernel<<<1, 128, 0, stream>>>(Psum2, sc, out);
}

// Round 14
// 29.957 us; speedup vs baseline: 1.1091x; 1.1091x over previous
//
#include <hip/hip_runtime.h>
#include <hip/hip_bf16.h>

#define NUM_CLASSES 10000
#define NUM_PROXIES 10
#define EMB_DIM 128
#define HALF_B 128
#define MARGIN_DELTA 0.01f
#define LAMBDA_ 20.0f
#define INV_GAMMA 10.0f   // 1/GAMMA

#define CB 8                        // classes per tile
#define ROWS (CB * NUM_PROXIES)     // 80 proxy rows per tile
#define MF 5                        // 80/16 m-fragments
#define KSTEPS 4                    // 128/32
#define NTILE 1250                  // 1250 blocks x 1 tile
#define TSTRIDE 164                 // bytes/col in transpose buf (41 words, odd)

#define SBYTES (ROWS * EMB_DIM * 2)        // 20480 B bf16 stage (aliased into C)
#define SMEMSZ (TSTRIDE * 256)             // 41984 B total LDS -> 3 blocks/CU

typedef __bf16 bf16x8 __attribute__((ext_vector_type(8)));
typedef __bf16 bf16x4 __attribute__((ext_vector_type(4)));
typedef float f32x4 __attribute__((ext_vector_type(4)));
typedef unsigned short ushort_t;

__device__ __forceinline__ unsigned int pk2bf(float a, float b) {
    __bf16 ha = (__bf16)a, hb = (__bf16)b;
    return (unsigned int)__builtin_bit_cast(ushort_t, ha) |
           ((unsigned int)__builtin_bit_cast(ushort_t, hb) << 16);
}

// ---------------------------------------------------------------------------
// Kernel 0: pack feat into MFMA B-fragment layout ONCE (64 KB, L2-resident).
// featPack[((w*4+nf)*4+t)*64 + lane] = bf16x8 of feat[col][t*32+g*8 .. +8),
// col = w*64+nf*16+(lane&15), g = lane>>4. Removes 1250x uncoalesced feat
// reloads (64 lines/instr -> L1-pipe bound; the round-3 +11.5us win).
// ---------------------------------------------------------------------------
__global__ __launch_bounds__(256) void pack_feat_kernel(
    const float* __restrict__ feat,    // [256][128] f32
    bf16x8* __restrict__ featPack)     // [4096] entries of 16 B
{
    const int gid = blockIdx.x * 256 + threadIdx.x;   // 0..2047
    #pragma unroll
    for (int half = 0; half < 2; ++half) {
        int e    = gid + half * 2048;                 // 0..4095
        int lane = e & 63;
        int t    = (e >> 6) & 3;
        int nf   = (e >> 8) & 3;
        int w    = (e >> 10) & 3;
        int l15  = lane & 15;
        int g    = lane >> 4;
        int col  = w * 64 + nf * 16 + l15;
        const float4* fp = (const float4*)(feat + (size_t)col * EMB_DIM + t * 32 + g * 8);
        float4 v0 = fp[0], v1 = fp[1];
        featPack[e] = (bf16x8){ (__bf16)v0.x, (__bf16)v0.y, (__bf16)v0.z, (__bf16)v0.w,
                                (__bf16)v1.x, (__bf16)v1.y, (__bf16)v1.z, (__bf16)v1.w };
    }
}

// ---------------------------------------------------------------------------
// Kernel 1: one tile per block, 1250 blocks. LDS: bf16 stage (20480 B)
// aliased into transpose buffer C (41984 B) -> 3 blocks/CU.
// bfrag comes from featPack: 16 coalesced 16B/lane loads.
// CHAMPION -- measured 30.0/30.1/30.4 us end-to-end (R10/R3/R12).
// Closed ledger (all controlled, all regressed): in-block 2-tile pipeline
// +5.4; fused tails +9/+9/+3 (device-fence > launch saving); two-pass
// softmax +2.4; 8-wave split +2.4; DMA f32-LDS +13 (FETCH 25.6->39.5MB);
// clean 4 blocks/CU +3 (cache contention > TLP gain). Do not re-derive.
// ---------------------------------------------------------------------------
__global__ __launch_bounds__(256, 3) void compute_S_kernel(
    const float* __restrict__ prox,     // [10000][10][128] f32
    const bf16x8* __restrict__ featPack,// [4096]
    const int* __restrict__ labels,     // [256]
    float* __restrict__ Ps,             // [1250][128]
    float* __restrict__ sc)             // [128]
{
    __shared__ __align__(16) char smem[SMEMSZ];

    const int tid     = threadIdx.x;
    const int lane    = tid & 63;
    const int w       = tid >> 6;
    const int l15     = lane & 15;
    const int g       = lane >> 4;
    const int tileIdx = blockIdx.x;
    const int lab     = labels[tid & 127];

    // ---- issue stage loads first (80x128 f32 tile, linear & coalesced) ----
    const char* pbase = (const char*)prox + (size_t)tileIdx * (ROWS * EMB_DIM * 4);
    float4 sv[10];
    #pragma unroll
    for (int j = 0; j < 10; ++j)
        sv[j] = *(const float4*)(pbase + ((size_t)(j * 256 + tid) << 4));

    // ---- B fragments: coalesced loads from packed layout (L2-hit) ----
    bf16x8 bfrag[4][KSTEPS];
    #pragma unroll
    for (int nf = 0; nf < 4; ++nf)
        #pragma unroll
        for (int t = 0; t < KSTEPS; ++t)
            bfrag[nf][t] = featPack[((w * 4 + nf) * 4 + t) * 64 + lane];

    // ---- convert stage to bf16, XOR-swizzled ds_write (once per value) ----
    // f32 16B-chunk cid = j*256+tid: row = cid>>5, c32 = cid&31.
    // bf16 chunk16 c16 = c32>>1 stored at slot (c16 ^ (row&7)), half (c32&1).
    #pragma unroll
    for (int j = 0; j < 10; ++j) {
        int cid = j * 256 + tid;
        int row = cid >> 5;
        int c32 = cid & 31;
        int off = row * 256 + ((((c32 >> 1) ^ (row & 7))) << 4) + ((c32 & 1) << 3);
        bf16x4 o = { (__bf16)sv[j].x, (__bf16)sv[j].y, (__bf16)sv[j].z, (__bf16)sv[j].w };
        *(bf16x4*)(smem + off) = o;
    }

    __syncthreads();

    // ---- MFMA: 20 ds_read_b128 + 80 MFMA per wave ----
    f32x4 acc[MF][4];
    #pragma unroll
    for (int mf = 0; mf < MF; ++mf)
        #pragma unroll
        for (int nf = 0; nf < 4; ++nf)
            acc[mf][nf] = (f32x4){0.f, 0.f, 0.f, 0.f};

    __builtin_amdgcn_s_setprio(1);
    #pragma unroll
    for (int t = 0; t < KSTEPS; ++t) {
        #pragma unroll
        for (int mf = 0; mf < MF; ++mf) {
            int row = mf * 16 + l15;
            int ck  = (t * 4 + g) ^ (row & 7);
            bf16x8 a = *(const bf16x8*)(smem + row * 256 + (ck << 4));
            #pragma unroll
            for (int nf = 0; nf < 4; ++nf)
                acc[mf][nf] = __builtin_amdgcn_mfma_f32_16x16x32_bf16(
                    a, bfrag[nf][t], acc[mf][nf], 0, 0, 0);
        }
    }
    __builtin_amdgcn_s_setprio(0);

    // WAR hazard: transpose writes overlap the (now dead) stage region.
    __syncthreads();

    // ---- transpose dots into C (bf16, stride 164B = 41 words) ----
    char* C = smem;
    #pragma unroll
    for (int mf = 0; mf < MF; ++mf) {
        #pragma unroll
        for (int nf = 0; nf < 4; ++nf) {
            int col  = w * 64 + nf * 16 + l15;
            int rowb = mf * 16 + g * 4;
            unsigned int lo = pk2bf(acc[mf][nf][0], acc[mf][nf][1]);
            unsigned int hi = pk2bf(acc[mf][nf][2], acc[mf][nf][3]);
            char* p = C + col * TSTRIDE + rowb * 2;
            *(unsigned int*)p       = lo;
            *(unsigned int*)(p + 4) = hi;
        }
    }
    __syncthreads();

    // ---- k=10 softmax per (col, class); pair-avg cols i / i+128 ----
    const int colh  = tid & 127;
    const int chalf = tid >> 7;
    float lsum = 0.f;
    #pragma unroll
    for (int cl4 = 0; cl4 < 4; ++cl4) {
        int cl = chalf * 4 + cl4;
        float Ssum = 0.f;
        #pragma unroll
        for (int h = 0; h < 2; ++h) {
            const char* base = C + (colh + h * 128) * TSTRIDE + cl * 20;
            float d[10];
            #pragma unroll
            for (int p5 = 0; p5 < 5; ++p5) {
                unsigned int pr = *(const unsigned int*)(base + p5 * 4);
                // exact-bit unpack: (pr&0xFFFF)<<16 == pr<<16 ; (pr>>16)<<16 == pr&0xFFFF0000
                d[2 * p5]     = __builtin_bit_cast(float, pr << 16);
                d[2 * p5 + 1] = __builtin_bit_cast(float, pr & 0xFFFF0000u);
            }
            float sw = 0.f, sd = 0.f;
            #pragma unroll
            for (int k = 0; k < NUM_PROXIES; ++k) {
                float e = __expf(d[k] * INV_GAMMA);   // no max-shift: bounded
                sw += e;
                sd += e * d[k];
            }
            Ssum += sd / sw;
        }
        float Savg = 0.5f * Ssum;
        int c = tileIdx * CB + cl;
        float x = LAMBDA_ * Savg;
        if (c == lab) {
            x -= LAMBDA_ * MARGIN_DELTA;
            sc[colh] = x;
        }
        lsum += __expf(x);
    }

    // rowsum lives in C's 4-byte pad word (byte 160 of each 164B column)
    *(float*)(C + tid * TSTRIDE + 160) = lsum;
    __syncthreads();
    if (tid < HALF_B) {
        float a = *(const float*)(C + tid * TSTRIDE + 160);
        float b = *(const float*)(C + (tid + 128) * TSTRIDE + 160);
        Ps[(size_t)tileIdx * HALF_B + tid] = a + b;
    }
}

// ---------------------------------------------------------------------------
// Kernel 2: coalesced partial sum of Ps over tiles. 50 blocks x 25 tiles.
// (Parallel shape is load-bearing: 1-block variants cost ~+9us.)
// ---------------------------------------------------------------------------
__global__ __launch_bounds__(256) void psum_kernel(
    const float* __restrict__ Ps,      // [1250][128]
    float* __restrict__ Psum2)         // [50][128]
{
    const int b0  = blockIdx.x * 25;
    const int tid = threadIdx.x;
    const int r   = tid >> 5;    // 0..7
    const int c   = tid & 31;    // float4 column group

    float4 s = make_float4(0.f, 0.f, 0.f, 0.f);
    #pragma unroll
    for (int j = 0; j < 4; ++j) {
        int b = r + 8 * j;
        if (b < 25) {
            float4 v = *(const float4*)(Ps + (size_t)(b0 + b) * HALF_B + c * 4);
            s.x += v.x; s.y += v.y; s.z += v.z; s.w += v.w;
        }
    }

    __shared__ float red[8][HALF_B];
    *(float4*)&red[r][c * 4] = s;
    __syncthreads();
    if (tid < HALF_B) {
        float t = 0.f;
        #pragma unroll
        for (int rr = 0; rr < 8; ++rr) t += red[rr][tid];
        Psum2[blockIdx.x * HALF_B + tid] = t;
    }
}

// ---------------------------------------------------------------------------
// Kernel 3: denom[i] = log(sum_b Psum2[b][i]); loss = -mean(sc[i]-denom[i])
// ---------------------------------------------------------------------------
__global__ __launch_bounds__(128) void finalize_kernel(
    const float* __restrict__ Psum2,   // [50][128]
    const float* __restrict__ sc,      // [128]
    float* __restrict__ out)
{
    const int i = threadIdx.x;   // 0..127
    float t = 0.f;
    #pragma unroll
    for (int b = 0; b < 50; ++b) t += Psum2[b * HALF_B + i];
    float part = sc[i] - __logf(t);

    __shared__ float buf[HALF_B];
    buf[i] = part;
    __syncthreads();
    #pragma unroll
    for (int off = 64; off >= 1; off >>= 1) {
        if (i < off) buf[i] += buf[i + off];
        __syncthreads();
    }
    if (i == 0) out[0] = -buf[0] / (float)HALF_B;
}

extern "C" void kernel_launch(void* const* d_in, const int* in_sizes, int n_in,
                              void* d_out, int out_size, void* d_ws, size_t ws_size,
                              hipStream_t stream) {
    const float* feat   = (const float*)d_in[0];   // [256][128] f32
    const int*   labels = (const int*)d_in[1];     // [256]
    const float* prox   = (const float*)d_in[2];   // [10000][10][128] f32
    float* out = (float*)d_out;

    float* Ps    = (float*)d_ws;                                   // 640000 B
    float* sc    = (float*)((char*)d_ws + 640000);                 // 512 B
    float* Psum2 = (float*)((char*)d_ws + 640512);                 // 25600 B
    bf16x8* featPack = (bf16x8*)((char*)d_ws + 666112);            // 65536 B

    pack_feat_kernel<<<8, 256, 0, stream>>>(feat, featPack);
    compute_S_kernel<<<NTILE, 256, 0, stream>>>(prox, featPack, labels, Ps, sc);
    psum_kernel<<<50, 256, 0, stream>>>(Ps, Psum2);
    finalize_kernel<<<1, 128, 0, stream>>>(Psum2, sc, out);
}